// Round 9
// baseline (353.301 us; speedup 1.0000x reference)
//
#include <hip/hip_runtime.h>
#include <hip/hip_bf16.h>

// Problem constants
#define B_   4
#define L_   2048
#define E_   1024
#define H_   16
#define T_   8192      // B_*L_
#define K_   1024

typedef __attribute__((ext_vector_type(8))) short bf16x8;   // 8 bf16 = 4 VGPRs
typedef __attribute__((ext_vector_type(4))) float f32x4;
typedef __attribute__((ext_vector_type(4))) unsigned u32x4;

#define CSC_ (0.125f * 1.44269504f)   // attn scale * log2(e), folded into Q

// fp32 -> bf16 round-to-nearest-even (scalar; epilogue paths only)
__device__ __forceinline__ ushort f2b(float f) {
    union { float f; unsigned u; } x; x.f = f;
    unsigned r = (x.u + 0x7fffu + ((x.u >> 16) & 1u)) >> 16;
    return (ushort)r;
}

// guaranteed-native exp2: single v_exp_f32 (libm exp2f adds range-fixup code)
__device__ __forceinline__ float fexp2(float x) {
#if __has_builtin(__builtin_amdgcn_exp2f)
    return __builtin_amdgcn_exp2f(x);
#else
    return __expf(x * 0.69314718056f);   // __expf = v_mul + v_exp (native)
#endif
}

// pack two fp32 -> (bf16 | bf16<<16), cheap rounding
__device__ __forceinline__ unsigned pack2bf(float a, float b) {
#if __has_builtin(__builtin_amdgcn_cvt_pk_bf16_f32)
    auto t = __builtin_amdgcn_cvt_pk_bf16_f32(a, b);
    return __builtin_bit_cast(unsigned, t);
#else
    // round-half-up to bf16 then merge high halves with one v_perm_b32
    unsigned ua = __builtin_bit_cast(unsigned, a) + 0x8000u;
    unsigned ub = __builtin_bit_cast(unsigned, b) + 0x8000u;
    return __builtin_amdgcn_perm(ub, ua, 0x07060302);  // {ub.b3,ub.b2,ua.b3,ua.b2}
#endif
}

// async global->LDS, 16B per lane, LDS dest = wave-uniform base + lane*16
#define GLD_LDS16(gp, lp) __builtin_amdgcn_global_load_lds( \
    (const __attribute__((address_space(1))) void*)(gp), \
    (__attribute__((address_space(3))) void*)(lp), 16, 0, 0)

// ---------------------------------------------------------------------------
// Mask layout detection (byte vs int32 bool).
// ---------------------------------------------------------------------------
__global__ void detect_mask_layout(const unsigned char* __restrict__ m, int* flag) {
    __shared__ int s;
    if (threadIdx.x == 0) s = 0;
    __syncthreads();
    int found = 0;
    for (int i = threadIdx.x; i < 4096; i += 256)
        if ((i & 3) != 0 && m[i] != 0) found = 1;
    if (found) atomicOr(&s, 1);
    __syncthreads();
    if (threadIdx.x == 0) *flag = s;   // 1 = byte layout, 0 = int32 layout
}

// Pack mask into TRANSPOSED u32 bit-planes: tbits[b][w32][q], w32 = 32-key
// tile index (64 per row). bit j of word = ATTEND for key w32*32+j.
__global__ void pack_mask(const void* __restrict__ mraw, const int* __restrict__ flag,
                          unsigned* __restrict__ tbits) {
    int row  = blockIdx.x;            // b*L_ + q
    int lane = threadIdx.x & 63;
    int wave = threadIdx.x >> 6;
    int isByte = *flag;
    int b = row >> 11, q = row & 2047;
    const unsigned char* mb = (const unsigned char*)mraw;
    const int*           mi = (const int*)mraw;
    long long base = (long long)row * L_;
    for (int w = wave; w < 32; w += 4) {
        int idx = w * 64 + lane;
        int v = isByte ? (int)mb[base + idx] : mi[base + idx];
        unsigned long long word = __ballot(v == 0);   // bit=1 -> ATTEND
        if (lane == 0) {
            tbits[((size_t)b * 64 + 2 * w)     * 2048 + q] = (unsigned)word;
            tbits[((size_t)b * 64 + 2 * w + 1) * 2048 + q] = (unsigned)(word >> 32);
        }
    }
}

// ---------------------------------------------------------------------------
// fp32 -> bf16 elementwise (embeddings)
// ---------------------------------------------------------------------------
__global__ __launch_bounds__(256) void conv_bf16(const float* __restrict__ in,
                                                 ushort* __restrict__ out) {
    int i = blockIdx.x * 256 + threadIdx.x;
    float4 v = ((const float4*)in)[i];
    uint2 o;
    o.x = (unsigned)f2b(v.x) | ((unsigned)f2b(v.y) << 16);
    o.y = (unsigned)f2b(v.z) | ((unsigned)f2b(v.w) << 16);
    ((uint2*)out)[i] = o;
}

// ---------------------------------------------------------------------------
// fp32 [R][Cn] -> bf16 transposed [Cn][R]  (weights -> B^T form)
// ---------------------------------------------------------------------------
__global__ __launch_bounds__(256) void transpose_conv(const float* __restrict__ in,
        ushort* __restrict__ out, int R, int Cn) {
    __shared__ float t[32][33];
    int c0 = blockIdx.x * 32, r0 = blockIdx.y * 32;
    int x = threadIdx.x & 31, y = threadIdx.x >> 5;   // y in 0..7
#pragma unroll
    for (int k = 0; k < 4; ++k)
        t[y + k * 8][x] = in[(size_t)(r0 + y + k * 8) * Cn + c0 + x];
    __syncthreads();
#pragma unroll
    for (int k = 0; k < 4; ++k)
        out[(size_t)(c0 + y + k * 8) * R + r0 + x] = f2b(t[x][y + k * 8]);
}

// ---------------------------------------------------------------------------
// bf16 MFMA GEMM: C[M][N] = A[M][1024] @ Bt[N][1024]^T
// 128x128 tile, 256 thr (4 waves, 2x2 wave grid, 4x4 16x16 tiles/wave).
// R15: BK=32 DOUBLE-BUFFER -- LDS 64->32 KB so 4-5 blocks/CU co-reside
// (R14's 64 KB dbuf capped at 2 blocks/CU, Occupancy 18.7%; in a lockstep
// 2-barrier loop cross-BLOCK overlap is what hides barrier drains, cf. the
// guide's m132: 3->2 blocks/CU cost 42%). Same 2-phase pipeline: stage(t+1)
// BEFORE compute(t), then __syncthreads (drain covered by compute).
// LDS swizzle: logical chunk c (8 elems) of row r stored at pos c^(r&3) via
// pre-swizzled per-lane GLOBAL source (GLD dest must stay linear); fragment
// read uses quad^(row16&3) -> 2 rows/4-bank group, conflict-free.
// Hazards: buf written iter t drained at iter-t barrier, read iter t+1;
// buf read iter t has its ds_reads retired pre-barrier (lgkmcnt before MFMA),
// overwritten iter t+1. Barriers block-uniform. Manual 2x unroll keeps
// buffer indices compile-time.
// MODE 0: write C fp32.  MODE 1: scatter bf16 into Q,K ([B*H][L][A]) and
// V transposed ([B*H][A][L]) with KEY PERMUTATION inside each 32-group:
// storage col c holds key 16*(c&1)+(c>>1).  Q pre-scaled by CSC_.
// ---------------------------------------------------------------------------
template<int NDIM, int MODE>
__global__ __launch_bounds__(256, 4) void gemm_bf16(
        const ushort* __restrict__ Ab, const ushort* __restrict__ Bt,
        float* __restrict__ Cg, ushort* __restrict__ Qb,
        ushort* __restrict__ Kb, ushort* __restrict__ Vt) {
    __shared__ ushort As[2][128 * 32];   // 2 x 8 KB
    __shared__ ushort Bs[2][128 * 32];   // 2 x 8 KB  (total 32 KB)
    const int tid = threadIdx.x;
    const int wv = tid >> 6, ln = tid & 63;
    const int bn = blockIdx.x * 128, bm = blockIdx.y * 128;
    const int wm = (wv & 1) * 64, wn = (wv >> 1) * 64;
    const int row16 = ln & 15, quad = ln >> 4;

    // staging: lane -> row-in-16 = ln>>2, stored pos = ln&3; source supplies
    // logical chunk cc = (ln&3) ^ (row&3) so LDS holds chunk c at pos c^(r&3)
    const int rr = ln >> 2;
    const int cc8 = (((ln & 3) ^ (rr & 3)) * 8);

    const ushort* Ag = Ab + (size_t)(bm + wv * 32 + rr) * K_ + cc8;
    const ushort* Bg = Bt + (size_t)(bn + wv * 32 + rr) * K_ + cc8;

    auto stage = [&](int k0, int buf) {
#pragma unroll
        for (int g = 0; g < 2; ++g) {
            GLD_LDS16(Ag + (size_t)(g * 16) * K_ + k0, &As[buf][(wv * 32 + g * 16) * 32]);
            GLD_LDS16(Bg + (size_t)(g * 16) * K_ + k0, &Bs[buf][(wv * 32 + g * 16) * 32]);
        }
    };

    f32x4 acc[4][4];
#pragma unroll
    for (int i = 0; i < 4; ++i)
#pragma unroll
        for (int j = 0; j < 4; ++j) acc[i][j] = (f32x4){0.f, 0.f, 0.f, 0.f};

    const int ch = (quad ^ (row16 & 3)) * 8;       // swizzled read chunk (elems)

    auto compute = [&](const ushort* Ac, const ushort* Bc) {
        bf16x8 af[4], bf[4];
#pragma unroll
        for (int i = 0; i < 4; ++i)
            af[i] = *(const bf16x8*)&Ac[(wm + i * 16 + row16) * 32 + ch];
#pragma unroll
        for (int j = 0; j < 4; ++j)
            bf[j] = *(const bf16x8*)&Bc[(wn + j * 16 + row16) * 32 + ch];
#pragma unroll
        for (int i = 0; i < 4; ++i)
#pragma unroll
            for (int j = 0; j < 4; ++j)
                acc[i][j] = __builtin_amdgcn_mfma_f32_16x16x32_bf16(
                    af[i], bf[j], acc[i][j], 0, 0, 0);
    };

    stage(0, 0);                                   // prologue: tile 0
    __syncthreads();                               // tile 0 landed

    for (int t = 0; t < 32; t += 2) {              // 32 BK=32 steps, 2x unrolled
        stage((t + 1) * 32, 1);                    // prefetch t+1 (always valid)
        compute(As[0], Bs[0]);
        __syncthreads();                           // t+1 landed under compute
        if (t + 2 < 32) stage((t + 2) * 32, 0);    // prefetch t+2
        compute(As[1], Bs[1]);
        __syncthreads();
    }

    if (MODE == 0) {
#pragma unroll
        for (int i = 0; i < 4; ++i)
#pragma unroll
            for (int j = 0; j < 4; ++j) {
                int col = bn + wn + j * 16 + row16;
#pragma unroll
                for (int r = 0; r < 4; ++r) {
                    int row = bm + wm + i * 16 + quad * 4 + r;
                    Cg[(size_t)row * NDIM + col] = acc[i][j][r];
                }
            }
    } else {
#pragma unroll
        for (int j = 0; j < 4; ++j) {
            int col = bn + wn + j * 16 + row16;
            int h = col / 192, w = col - h * 192;
            int sel = w >> 6, a = w & 63;
            float qs = (sel == 0) ? CSC_ : 1.0f;   // fold softmax scale into Q
#pragma unroll
            for (int i = 0; i < 4; ++i)
#pragma unroll
                for (int r = 0; r < 4; ++r) {
                    int rowg = bm + wm + i * 16 + quad * 4 + r;
                    int b = rowg >> 11, l = rowg & 2047;
                    ushort v = f2b(acc[i][j][r] * qs);
                    size_t bh = (size_t)(b * H_ + h);
                    if (sel == 0)      Qb[(bh * L_ + l) * 64 + a] = v;
                    else if (sel == 1) Kb[(bh * L_ + l) * 64 + a] = v;
                    else {
                        // key-permute within 32-group: pos c <-> key 16*(c&1)+(c>>1)
                        int k5 = l & 31;
                        int lp = (l & ~31) | (2 * (k5 & 15) + (k5 >> 4));
                        Vt[(bh * 64 + a) * L_ + lp] = v;
                    }
                }
        }
    }
}

// ---------------------------------------------------------------------------
// MFMA flash attention R12 (unchanged, passed at ~90 us): 32 q-rows/wave
// (2 row-groups), 256-row blocks, 512 blocks = exactly 2 blocks/CU.
// Triple-buffered K/V + counted-vmcnt raw barrier; grid (bh, qtile) for
// same-XCD L2 sharing; swapped QK^T (mfma(K,Q)=S^T) with V key-permute so
// P stays lane-local. l==0 => fully-masked row => output 0.
// ---------------------------------------------------------------------------
__global__ __launch_bounds__(512, 4) void attn_mfma(
        const ushort* __restrict__ Qb, const ushort* __restrict__ Kb,
        const ushort* __restrict__ Vt, const unsigned* __restrict__ tbits,
        ushort* __restrict__ vals) {
    __shared__ ushort KV[6][4096];   // K bufs 0..2, V bufs 3..5 (8 KB each)

    const int tid = threadIdx.x, wv = tid >> 6, ln = tid & 63;
    const int bh = blockIdx.x, b = bh >> 4, h = bh & 15;
    const int q0 = blockIdx.y * 256;
    const int row16 = ln & 15, quad = ln >> 4;
    const int lh = ln >> 3, ll = ln & 7;          // staging: row-in-8 / chunk-pos
    const int cg8 = ((ll ^ lh) * 8);              // XOR-swizzled source chunk

    const ushort* Kg = Kb + (size_t)bh * L_ * 64;
    const ushort* Vg = Vt + (size_t)bh * 64 * L_;

    // staging roles: waves 0-3 stage K rows, waves 4-7 stage V
    const int wk = wv & 3;
    const bool isK = (wv < 4);
    // V staging source (paired-row layout): buf row r=wk*8+lh holds a-rows
    // {r, r+32}; stored chunk ll <- logical chunk c=ll^lh.
    const int vc4 = ll ^ lh;
    const ushort* vstage = Vg + (size_t)(wk * 8 + lh + 32 * (vc4 >> 2)) * L_ + (vc4 & 3) * 8;
    const ushort* kstage = Kg + (size_t)(wk * 8 + lh) * 64 + cg8;

    ushort* lds = &KV[0][0];

    // ---- stage Q (own 32 rows, 4 KB) into KV[0..3] region, hoist frags ----
    {
        const ushort* Qgw = Qb + ((size_t)bh * L_ + q0 + wv * 32) * 64;
#pragma unroll
        for (int it = 0; it < 4; ++it)
            GLD_LDS16(Qgw + (size_t)(it * 8 + lh) * 64 + cg8,
                      lds + (wv * 32 + it * 8) * 64);
    }
    __syncthreads();
    bf16x8 aq[2][2];
#pragma unroll
    for (int rg = 0; rg < 2; ++rg)
#pragma unroll
        for (int ks = 0; ks < 2; ++ks)
            aq[rg][ks] = *(const bf16x8*)&lds[(wv * 32 + rg * 16 + row16) * 64 +
                                              (((ks * 4 + quad) ^ (row16 & 7)) * 8)];
    __syncthreads();   // Q reads done (full drain) before K staging overwrites

    // ---- stage tiles 0 and 1 into bufs {0,3} and {1,4} ----
    if (isK) {
        GLD_LDS16(kstage,               &KV[0][(wk * 8) * 64]);
        GLD_LDS16(kstage + 2048,        &KV[0][(32 + wk * 8) * 64]);
        GLD_LDS16(kstage + 4096,        &KV[1][(wk * 8) * 64]);
        GLD_LDS16(kstage + 4096 + 2048, &KV[1][(32 + wk * 8) * 64]);
        kstage += 8192;
    } else {
        GLD_LDS16(vstage,      &KV[3][(wk * 8) * 64]);
        GLD_LDS16(vstage + 32, &KV[3][(32 + wk * 8) * 64]);
        GLD_LDS16(vstage + 64, &KV[4][(wk * 8) * 64]);
        GLD_LDS16(vstage + 96, &KV[4][(32 + wk * 8) * 64]);
        vstage += 128;
    }

    bf16x8 vone;
#pragma unroll
    for (int i = 0; i < 8; ++i) vone[i] = (short)0x3F80;   // bf16 1.0
    const f32x4 zf = (f32x4){0.f, 0.f, 0.f, 0.f};

    f32x4 oacc[2][4], lacc[2];
#pragma unroll
    for (int rg = 0; rg < 2; ++rg) {
        lacc[rg] = zf;
#pragma unroll
        for (int t = 0; t < 4; ++t) oacc[rg][t] = zf;
    }

    // transposed mask: word per lane per 32-key tile; row-group rg word at
    // offset rg*16 (q-row = q0 + wv*32 + rg*16 + row16)
    const unsigned* mptr = tbits + (size_t)b * 64 * 2048 + (q0 + wv * 32 + row16);

    // ---- swapped QK on 32-key sub-tile: S^T for both row-groups ----
    auto qk = [&](const ushort* kbuf, int sub, f32x4 (&s)[2][2]) {
        __builtin_amdgcn_s_setprio(1);
#pragma unroll
        for (int ks = 0; ks < 2; ++ks) {
            bf16x8 bk[2];
#pragma unroll
            for (int t = 0; t < 2; ++t)
                bk[t] = *(const bf16x8*)&kbuf[(sub * 32 + t * 16 + row16) * 64 +
                                              (((ks * 4 + quad) ^ (row16 & 7)) * 8)];
#pragma unroll
            for (int rg = 0; rg < 2; ++rg)
#pragma unroll
                for (int t = 0; t < 2; ++t)
                    s[rg][t] = __builtin_amdgcn_mfma_f32_16x16x32_bf16(
                        bk[t], aq[rg][ks], ks ? s[rg][t] : zf, 0, 0, 0);
        }
        __builtin_amdgcn_s_setprio(0);
    };

    // ---- masked exp2 -> packed P (registers) -> PV accumulate ----
    // s[rg][t][r] = S[q=rg*16+row16][k = t*16 + quad*4 + r]; packed word r =
    // permuted slots 8*quad+2r (lo) and +1 (hi) => pw IS the A-fragment.
    auto sm_pv = [&](f32x4 (&sa)[2][2], unsigned mlo, unsigned mhi,
                     const ushort* vbuf, int sub) {
        bf16x8 ap[2];
#pragma unroll
        for (int rg = 0; rg < 2; ++rg) {
            unsigned wr = rg ? mhi : mlo;
            u32x4 pw;
#pragma unroll
            for (int r = 0; r < 4; ++r) {
                unsigned sh = wr >> (quad * 4 + r);   // bits 0,16 = packed keys
                unsigned pk = pack2bf(fexp2(sa[rg][0][r]), fexp2(sa[rg][1][r]));
                pk &= (sh & 0x00010001u) * 0xFFFFu;   // bit -> halfword expand
                pw[r] = pk;
            }
            ap[rg] = __builtin_bit_cast(bf16x8, pw);
        }
        bf16x8 bv[4];
#pragma unroll
        for (int t = 0; t < 4; ++t)
            bv[t] = *(const bf16x8*)&vbuf[(sub * 32 + (t & 1) * 16 + row16) * 64 +
                                          ((((t >> 1) * 4 + quad) ^ (row16 & 7)) * 8)];
        __builtin_amdgcn_s_setprio(1);
#pragma unroll
        for (int rg = 0; rg < 2; ++rg) {
            lacc[rg] = __builtin_amdgcn_mfma_f32_16x16x32_bf16(
                ap[rg], vone, lacc[rg], 0, 0, 0);
#pragma unroll
            for (int t = 0; t < 4; ++t)
                oacc[rg][t] = __builtin_amdgcn_mfma_f32_16x16x32_bf16(
                    ap[rg], bv[t], oacc[rg][t], 0, 0, 0);
        }
        __builtin_amdgcn_s_setprio(0);
    };

    // ---- one 64-key iteration; kb/vb current bufs, kn/vn stage targets ----
    auto iter = [&](const ushort* kb, const ushort* vb,
                    ushort* kn, ushort* vn, bool st) {
        unsigned m0lo = mptr[0],    m0hi = mptr[16];
        unsigned m1lo = mptr[2048], m1hi = mptr[2048 + 16];
        mptr += 4096;
        __builtin_amdgcn_sched_barrier(0);         // masks issue BEFORE stages
        if (st) {                                  // stage tile kt+2
            if (isK) {
                GLD_LDS16(kstage,        kn + (wk * 8) * 64);
                GLD_LDS16(kstage + 2048, kn + (32 + wk * 8) * 64);
                kstage += 4096;
            } else {
                GLD_LDS16(vstage,      vn + (wk * 8) * 64);
                GLD_LDS16(vstage + 32, vn + (32 + wk * 8) * 64);
                vstage += 64;
            }
        }
        f32x4 s0[2][2];
        qk(kb, 0, s0);
        sm_pv(s0, m0lo, m0hi, vb, 0);              // mask-wait retires stage(kt+1)
        f32x4 s1[2][2];
        qk(kb, 1, s1);
        sm_pv(s1, m1lo, m1hi, vb, 1);
        asm volatile("s_waitcnt vmcnt(2)" ::: "memory");  // stage(kt+2) stays in flight
        __builtin_amdgcn_s_barrier();
        __builtin_amdgcn_sched_barrier(0);         // no ds_read hoist above barrier
    };

    // prologue barrier: tile-0 loads done (vmcnt(2): tile-1's 2 may fly)
    asm volatile("s_waitcnt vmcnt(2)" ::: "memory");
    __builtin_amdgcn_s_barrier();
    __builtin_amdgcn_sched_barrier(0);

    // 32 iterations, buffers cycle mod 3: kt=3g..3g+2 for g=0..9, then 30,31.
    for (int g = 0; g < 10; ++g) {
        iter(KV[0], KV[3], KV[2], KV[5], true);    // kt=3g:   read buf0, stage buf2
        iter(KV[1], KV[4], KV[0], KV[3], true);    // kt=3g+1: read buf1, stage buf0
        iter(KV[2], KV[5], KV[1], KV[4], true);    // kt=3g+2: read buf2, stage buf1
    }
    iter(KV[0], KV[3], KV[2], KV[5], false);       // kt=30
    iter(KV[1], KV[4], KV[0], KV[3], false);       // kt=31

    // ---- epilogue: /l (0 if fully masked), write vals bf16 [T][E] ----
#pragma unroll
    for (int rg = 0; rg < 2; ++rg)
#pragma unroll
        for (int r = 0; r < 4; ++r) {
            float l = lacc[rg][r];
            float inv = (l > 0.f) ? 1.0f / l : 0.f;
            int qrow = q0 + wv * 32 + rg * 16 + quad * 4 + r;
            size_t base = ((size_t)b * L_ + qrow) * E_ + h * 64;
#pragma unroll
            for (int t = 0; t < 4; ++t)
                vals[base + t * 16 + row16] = f2b(oacc[rg][t][r] * inv);
        }
}

// ---------------------------------------------------------------------------
// Launch
// ---------------------------------------------------------------------------
extern "C" void kernel_launch(void* const* d_in, const int* in_sizes, int n_in,
                              void* d_out, int out_size, void* d_ws, size_t ws_size,
                              hipStream_t stream) {
    const float* emb  = (const float*)d_in[0];
    const void*  mask = d_in[1];
    const float* wqkv = (const float*)d_in[2];
    const float* wout = (const float*)d_in[3];
    float* out = (float*)d_out;

    char* ws = (char*)d_ws;
    const size_t NEED = 4096ull + 2097152ull + 2ull * 46137344ull;
    if (ws_size < NEED) return;

    int* flag = (int*)ws;
    unsigned* tbits = (unsigned*)(ws + 4096);          // 2 MB, [b][w32][q]
    ushort* embb  = (ushort*)(ws + 4096 + 2097152);
    ushort* Wqkvt = embb  + 8388608;   // [3072][1024]
    ushort* Wott  = Wqkvt + 3145728;   // [1024][1024]
    ushort* Qb    = Wott  + 1048576;   // [B*H][L][A]  (pre-scaled by CSC_)
    ushort* Kb    = Qb    + 8388608;   // [B*H][L][A]
    ushort* Vt    = Kb    + 8388608;   // [B*H][A][L]  (key-permuted in 32-groups)
    ushort* vals  = Vt    + 8388608;   // [T][E] bf16

    detect_mask_layout<<<1, 256, 0, stream>>>((const unsigned char*)mask, flag);
    pack_mask<<<T_, 256, 0, stream>>>(mask, flag, tbits);
    conv_bf16<<<8192, 256, 0, stream>>>(emb, embb);
    transpose_conv<<<dim3(96, 32), 256, 0, stream>>>(wqkv, Wqkvt, 1024, 3072);
    transpose_conv<<<dim3(32, 32), 256, 0, stream>>>(wout, Wott, 1024, 1024);
    gemm_bf16<3072, 1><<<dim3(24, 64), 256, 0, stream>>>(
        embb, Wqkvt, nullptr, Qb, Kb, Vt);
    attn_mfma<<<dim3(64, 8), 512, 0, stream>>>(Qb, Kb, Vt, tbits, vals);
    gemm_bf16<1024, 0><<<dim3(8, 64), 256, 0, stream>>>(
        vals, Wott, out, nullptr, nullptr, nullptr);
}

// Round 10
// 351.286 us; speedup vs baseline: 1.0057x; 1.0057x over previous
//
#include <hip/hip_runtime.h>
#include <hip/hip_bf16.h>

// Problem constants
#define B_   4
#define L_   2048
#define E_   1024
#define H_   16
#define T_   8192      // B_*L_
#define K_   1024

typedef __attribute__((ext_vector_type(8))) short bf16x8;   // 8 bf16 = 4 VGPRs
typedef __attribute__((ext_vector_type(4))) float f32x4;
typedef __attribute__((ext_vector_type(4))) unsigned u32x4;

#define CSC_ (0.125f * 1.44269504f)   // attn scale * log2(e), folded into Q

// fp32 -> bf16 round-to-nearest-even (scalar; epilogue paths only)
__device__ __forceinline__ ushort f2b(float f) {
    union { float f; unsigned u; } x; x.f = f;
    unsigned r = (x.u + 0x7fffu + ((x.u >> 16) & 1u)) >> 16;
    return (ushort)r;
}

// guaranteed-native exp2: single v_exp_f32 (libm exp2f adds range-fixup code)
__device__ __forceinline__ float fexp2(float x) {
#if __has_builtin(__builtin_amdgcn_exp2f)
    return __builtin_amdgcn_exp2f(x);
#else
    return __expf(x * 0.69314718056f);   // __expf = v_mul + v_exp (native)
#endif
}

// pack two fp32 -> (bf16 | bf16<<16), cheap rounding
__device__ __forceinline__ unsigned pack2bf(float a, float b) {
#if __has_builtin(__builtin_amdgcn_cvt_pk_bf16_f32)
    auto t = __builtin_amdgcn_cvt_pk_bf16_f32(a, b);
    return __builtin_bit_cast(unsigned, t);
#else
    // round-half-up to bf16 then merge high halves with one v_perm_b32
    unsigned ua = __builtin_bit_cast(unsigned, a) + 0x8000u;
    unsigned ub = __builtin_bit_cast(unsigned, b) + 0x8000u;
    return __builtin_amdgcn_perm(ub, ua, 0x07060302);  // {ub.b3,ub.b2,ua.b3,ua.b2}
#endif
}

// async global->LDS, 16B per lane, LDS dest = wave-uniform base + lane*16
#define GLD_LDS16(gp, lp) __builtin_amdgcn_global_load_lds( \
    (const __attribute__((address_space(1))) void*)(gp), \
    (__attribute__((address_space(3))) void*)(lp), 16, 0, 0)

// ---------------------------------------------------------------------------
// Mask layout detection (byte vs int32 bool).
// ---------------------------------------------------------------------------
__global__ void detect_mask_layout(const unsigned char* __restrict__ m, int* flag) {
    __shared__ int s;
    if (threadIdx.x == 0) s = 0;
    __syncthreads();
    int found = 0;
    for (int i = threadIdx.x; i < 4096; i += 256)
        if ((i & 3) != 0 && m[i] != 0) found = 1;
    if (found) atomicOr(&s, 1);
    __syncthreads();
    if (threadIdx.x == 0) *flag = s;   // 1 = byte layout, 0 = int32 layout
}

// Pack mask into TRANSPOSED u32 bit-planes: tbits[b][w32][q], w32 = 32-key
// tile index (64 per row). bit j of word = ATTEND for key w32*32+j.
__global__ void pack_mask(const void* __restrict__ mraw, const int* __restrict__ flag,
                          unsigned* __restrict__ tbits) {
    int row  = blockIdx.x;            // b*L_ + q
    int lane = threadIdx.x & 63;
    int wave = threadIdx.x >> 6;
    int isByte = *flag;
    int b = row >> 11, q = row & 2047;
    const unsigned char* mb = (const unsigned char*)mraw;
    const int*           mi = (const int*)mraw;
    long long base = (long long)row * L_;
    for (int w = wave; w < 32; w += 4) {
        int idx = w * 64 + lane;
        int v = isByte ? (int)mb[base + idx] : mi[base + idx];
        unsigned long long word = __ballot(v == 0);   // bit=1 -> ATTEND
        if (lane == 0) {
            tbits[((size_t)b * 64 + 2 * w)     * 2048 + q] = (unsigned)word;
            tbits[((size_t)b * 64 + 2 * w + 1) * 2048 + q] = (unsigned)(word >> 32);
        }
    }
}

// ---------------------------------------------------------------------------
// fp32 -> bf16 elementwise (embeddings)
// ---------------------------------------------------------------------------
__global__ __launch_bounds__(256) void conv_bf16(const float* __restrict__ in,
                                                 ushort* __restrict__ out) {
    int i = blockIdx.x * 256 + threadIdx.x;
    float4 v = ((const float4*)in)[i];
    uint2 o;
    o.x = (unsigned)f2b(v.x) | ((unsigned)f2b(v.y) << 16);
    o.y = (unsigned)f2b(v.z) | ((unsigned)f2b(v.w) << 16);
    ((uint2*)out)[i] = o;
}

// ---------------------------------------------------------------------------
// fp32 [R][Cn] -> bf16 transposed [Cn][R]  (weights -> B^T form)
// ---------------------------------------------------------------------------
__global__ __launch_bounds__(256) void transpose_conv(const float* __restrict__ in,
        ushort* __restrict__ out, int R, int Cn) {
    __shared__ float t[32][33];
    int c0 = blockIdx.x * 32, r0 = blockIdx.y * 32;
    int x = threadIdx.x & 31, y = threadIdx.x >> 5;   // y in 0..7
#pragma unroll
    for (int k = 0; k < 4; ++k)
        t[y + k * 8][x] = in[(size_t)(r0 + y + k * 8) * Cn + c0 + x];
    __syncthreads();
#pragma unroll
    for (int k = 0; k < 4; ++k)
        out[(size_t)(c0 + y + k * 8) * R + r0 + x] = f2b(t[x][y + k * 8]);
}

// ---------------------------------------------------------------------------
// bf16 MFMA GEMM: C[M][N] = A[M][1024] @ Bt[N][1024]^T
// 128x128 tile, 256 thr (4 waves, 2x2 wave grid, 4x4 16x16 tiles/wave).
// R16: BK=32 double-buffer (32 KB LDS, 4+ blocks/CU) with FIXED swizzle.
// R15's bug: 64B rows put (row&1) into the bank-group address, and the XOR
// used row16&3 whose bit0 IS row&1 -> only 4 distinct groups/16-lane phase
// = 4-way conflict (6.29M SQ_LDS_BANK_CONFLICT). Fix: XOR with (row>>1)&3:
// group = (row&1, quad^((row16>>1)&3)) spans all 8 groups, 2 lanes each =
// conflict-free (same property as the proven BK=64 row16&7 design).
// Stored pos p of row r holds logical chunk p^((r>>1)&3) via pre-swizzled
// per-lane GLOBAL source (GLD dest stays linear); read pos quad^((row16>>1)&3)
// retrieves chunk quad. 2-phase pipeline: stage(t+1) BEFORE compute(t), then
// __syncthreads (drain covered by compute). Hazards as R14. 2x unroll keeps
// buffer indices compile-time.
// MODE 0: write C fp32.  MODE 1: scatter bf16 into Q,K ([B*H][L][A]) and
// V transposed ([B*H][A][L]) with KEY PERMUTATION inside each 32-group:
// storage col c holds key 16*(c&1)+(c>>1).  Q pre-scaled by CSC_.
// ---------------------------------------------------------------------------
template<int NDIM, int MODE>
__global__ __launch_bounds__(256, 4) void gemm_bf16(
        const ushort* __restrict__ Ab, const ushort* __restrict__ Bt,
        float* __restrict__ Cg, ushort* __restrict__ Qb,
        ushort* __restrict__ Kb, ushort* __restrict__ Vt) {
    __shared__ ushort As[2][128 * 32];   // 2 x 8 KB
    __shared__ ushort Bs[2][128 * 32];   // 2 x 8 KB  (total 32 KB)
    const int tid = threadIdx.x;
    const int wv = tid >> 6, ln = tid & 63;
    const int bn = blockIdx.x * 128, bm = blockIdx.y * 128;
    const int wm = (wv & 1) * 64, wn = (wv >> 1) * 64;
    const int row16 = ln & 15, quad = ln >> 4;

    // staging: lane -> row-in-16 = ln>>2, stored pos = ln&3; source supplies
    // logical chunk cc = (ln&3) ^ ((rr>>1)&3) so pos p holds chunk p^((r>>1)&3)
    const int rr = ln >> 2;
    const int cc8 = (((ln & 3) ^ ((rr >> 1) & 3)) * 8);

    const ushort* Ag = Ab + (size_t)(bm + wv * 32 + rr) * K_ + cc8;
    const ushort* Bg = Bt + (size_t)(bn + wv * 32 + rr) * K_ + cc8;

    auto stage = [&](int k0, int buf) {
#pragma unroll
        for (int g = 0; g < 2; ++g) {
            GLD_LDS16(Ag + (size_t)(g * 16) * K_ + k0, &As[buf][(wv * 32 + g * 16) * 32]);
            GLD_LDS16(Bg + (size_t)(g * 16) * K_ + k0, &Bs[buf][(wv * 32 + g * 16) * 32]);
        }
    };

    f32x4 acc[4][4];
#pragma unroll
    for (int i = 0; i < 4; ++i)
#pragma unroll
        for (int j = 0; j < 4; ++j) acc[i][j] = (f32x4){0.f, 0.f, 0.f, 0.f};

    const int ch = (quad ^ ((row16 >> 1) & 3)) * 8;   // swizzled read pos (elems)

    auto compute = [&](const ushort* Ac, const ushort* Bc) {
        bf16x8 af[4], bf[4];
#pragma unroll
        for (int i = 0; i < 4; ++i)
            af[i] = *(const bf16x8*)&Ac[(wm + i * 16 + row16) * 32 + ch];
#pragma unroll
        for (int j = 0; j < 4; ++j)
            bf[j] = *(const bf16x8*)&Bc[(wn + j * 16 + row16) * 32 + ch];
#pragma unroll
        for (int i = 0; i < 4; ++i)
#pragma unroll
            for (int j = 0; j < 4; ++j)
                acc[i][j] = __builtin_amdgcn_mfma_f32_16x16x32_bf16(
                    af[i], bf[j], acc[i][j], 0, 0, 0);
    };

    stage(0, 0);                                   // prologue: tile 0
    __syncthreads();                               // tile 0 landed

    for (int t = 0; t < 32; t += 2) {              // 32 BK=32 steps, 2x unrolled
        stage((t + 1) * 32, 1);                    // prefetch t+1 (always valid)
        compute(As[0], Bs[0]);
        __syncthreads();                           // t+1 landed under compute
        if (t + 2 < 32) stage((t + 2) * 32, 0);    // prefetch t+2
        compute(As[1], Bs[1]);
        __syncthreads();
    }

    if (MODE == 0) {
#pragma unroll
        for (int i = 0; i < 4; ++i)
#pragma unroll
            for (int j = 0; j < 4; ++j) {
                int col = bn + wn + j * 16 + row16;
#pragma unroll
                for (int r = 0; r < 4; ++r) {
                    int row = bm + wm + i * 16 + quad * 4 + r;
                    Cg[(size_t)row * NDIM + col] = acc[i][j][r];
                }
            }
    } else {
#pragma unroll
        for (int j = 0; j < 4; ++j) {
            int col = bn + wn + j * 16 + row16;
            int h = col / 192, w = col - h * 192;
            int sel = w >> 6, a = w & 63;
            float qs = (sel == 0) ? CSC_ : 1.0f;   // fold softmax scale into Q
#pragma unroll
            for (int i = 0; i < 4; ++i)
#pragma unroll
                for (int r = 0; r < 4; ++r) {
                    int rowg = bm + wm + i * 16 + quad * 4 + r;
                    int b = rowg >> 11, l = rowg & 2047;
                    ushort v = f2b(acc[i][j][r] * qs);
                    size_t bh = (size_t)(b * H_ + h);
                    if (sel == 0)      Qb[(bh * L_ + l) * 64 + a] = v;
                    else if (sel == 1) Kb[(bh * L_ + l) * 64 + a] = v;
                    else {
                        // key-permute within 32-group: pos c <-> key 16*(c&1)+(c>>1)
                        int k5 = l & 31;
                        int lp = (l & ~31) | (2 * (k5 & 15) + (k5 >> 4));
                        Vt[(bh * 64 + a) * L_ + lp] = v;
                    }
                }
        }
    }
}

// ---------------------------------------------------------------------------
// MFMA flash attention R12 (unchanged, passed at ~90 us): 32 q-rows/wave
// (2 row-groups), 256-row blocks, 512 blocks = exactly 2 blocks/CU.
// Triple-buffered K/V + counted-vmcnt raw barrier; grid (bh, qtile) for
// same-XCD L2 sharing; swapped QK^T (mfma(K,Q)=S^T) with V key-permute so
// P stays lane-local. l==0 => fully-masked row => output 0.
// ---------------------------------------------------------------------------
__global__ __launch_bounds__(512, 4) void attn_mfma(
        const ushort* __restrict__ Qb, const ushort* __restrict__ Kb,
        const ushort* __restrict__ Vt, const unsigned* __restrict__ tbits,
        ushort* __restrict__ vals) {
    __shared__ ushort KV[6][4096];   // K bufs 0..2, V bufs 3..5 (8 KB each)

    const int tid = threadIdx.x, wv = tid >> 6, ln = tid & 63;
    const int bh = blockIdx.x, b = bh >> 4, h = bh & 15;
    const int q0 = blockIdx.y * 256;
    const int row16 = ln & 15, quad = ln >> 4;
    const int lh = ln >> 3, ll = ln & 7;          // staging: row-in-8 / chunk-pos
    const int cg8 = ((ll ^ lh) * 8);              // XOR-swizzled source chunk

    const ushort* Kg = Kb + (size_t)bh * L_ * 64;
    const ushort* Vg = Vt + (size_t)bh * 64 * L_;

    // staging roles: waves 0-3 stage K rows, waves 4-7 stage V
    const int wk = wv & 3;
    const bool isK = (wv < 4);
    // V staging source (paired-row layout): buf row r=wk*8+lh holds a-rows
    // {r, r+32}; stored chunk ll <- logical chunk c=ll^lh.
    const int vc4 = ll ^ lh;
    const ushort* vstage = Vg + (size_t)(wk * 8 + lh + 32 * (vc4 >> 2)) * L_ + (vc4 & 3) * 8;
    const ushort* kstage = Kg + (size_t)(wk * 8 + lh) * 64 + cg8;

    ushort* lds = &KV[0][0];

    // ---- stage Q (own 32 rows, 4 KB) into KV[0..3] region, hoist frags ----
    {
        const ushort* Qgw = Qb + ((size_t)bh * L_ + q0 + wv * 32) * 64;
#pragma unroll
        for (int it = 0; it < 4; ++it)
            GLD_LDS16(Qgw + (size_t)(it * 8 + lh) * 64 + cg8,
                      lds + (wv * 32 + it * 8) * 64);
    }
    __syncthreads();
    bf16x8 aq[2][2];
#pragma unroll
    for (int rg = 0; rg < 2; ++rg)
#pragma unroll
        for (int ks = 0; ks < 2; ++ks)
            aq[rg][ks] = *(const bf16x8*)&lds[(wv * 32 + rg * 16 + row16) * 64 +
                                              (((ks * 4 + quad) ^ (row16 & 7)) * 8)];
    __syncthreads();   // Q reads done (full drain) before K staging overwrites

    // ---- stage tiles 0 and 1 into bufs {0,3} and {1,4} ----
    if (isK) {
        GLD_LDS16(kstage,               &KV[0][(wk * 8) * 64]);
        GLD_LDS16(kstage + 2048,        &KV[0][(32 + wk * 8) * 64]);
        GLD_LDS16(kstage + 4096,        &KV[1][(wk * 8) * 64]);
        GLD_LDS16(kstage + 4096 + 2048, &KV[1][(32 + wk * 8) * 64]);
        kstage += 8192;
    } else {
        GLD_LDS16(vstage,      &KV[3][(wk * 8) * 64]);
        GLD_LDS16(vstage + 32, &KV[3][(32 + wk * 8) * 64]);
        GLD_LDS16(vstage + 64, &KV[4][(wk * 8) * 64]);
        GLD_LDS16(vstage + 96, &KV[4][(32 + wk * 8) * 64]);
        vstage += 128;
    }

    bf16x8 vone;
#pragma unroll
    for (int i = 0; i < 8; ++i) vone[i] = (short)0x3F80;   // bf16 1.0
    const f32x4 zf = (f32x4){0.f, 0.f, 0.f, 0.f};

    f32x4 oacc[2][4], lacc[2];
#pragma unroll
    for (int rg = 0; rg < 2; ++rg) {
        lacc[rg] = zf;
#pragma unroll
        for (int t = 0; t < 4; ++t) oacc[rg][t] = zf;
    }

    // transposed mask: word per lane per 32-key tile; row-group rg word at
    // offset rg*16 (q-row = q0 + wv*32 + rg*16 + row16)
    const unsigned* mptr = tbits + (size_t)b * 64 * 2048 + (q0 + wv * 32 + row16);

    // ---- swapped QK on 32-key sub-tile: S^T for both row-groups ----
    auto qk = [&](const ushort* kbuf, int sub, f32x4 (&s)[2][2]) {
        __builtin_amdgcn_s_setprio(1);
#pragma unroll
        for (int ks = 0; ks < 2; ++ks) {
            bf16x8 bk[2];
#pragma unroll
            for (int t = 0; t < 2; ++t)
                bk[t] = *(const bf16x8*)&kbuf[(sub * 32 + t * 16 + row16) * 64 +
                                              (((ks * 4 + quad) ^ (row16 & 7)) * 8)];
#pragma unroll
            for (int rg = 0; rg < 2; ++rg)
#pragma unroll
                for (int t = 0; t < 2; ++t)
                    s[rg][t] = __builtin_amdgcn_mfma_f32_16x16x32_bf16(
                        bk[t], aq[rg][ks], ks ? s[rg][t] : zf, 0, 0, 0);
        }
        __builtin_amdgcn_s_setprio(0);
    };

    // ---- masked exp2 -> packed P (registers) -> PV accumulate ----
    // s[rg][t][r] = S[q=rg*16+row16][k = t*16 + quad*4 + r]; packed word r =
    // permuted slots 8*quad+2r (lo) and +1 (hi) => pw IS the A-fragment.
    auto sm_pv = [&](f32x4 (&sa)[2][2], unsigned mlo, unsigned mhi,
                     const ushort* vbuf, int sub) {
        bf16x8 ap[2];
#pragma unroll
        for (int rg = 0; rg < 2; ++rg) {
            unsigned wr = rg ? mhi : mlo;
            u32x4 pw;
#pragma unroll
            for (int r = 0; r < 4; ++r) {
                unsigned sh = wr >> (quad * 4 + r);   // bits 0,16 = packed keys
                unsigned pk = pack2bf(fexp2(sa[rg][0][r]), fexp2(sa[rg][1][r]));
                pk &= (sh & 0x00010001u) * 0xFFFFu;   // bit -> halfword expand
                pw[r] = pk;
            }
            ap[rg] = __builtin_bit_cast(bf16x8, pw);
        }
        bf16x8 bv[4];
#pragma unroll
        for (int t = 0; t < 4; ++t)
            bv[t] = *(const bf16x8*)&vbuf[(sub * 32 + (t & 1) * 16 + row16) * 64 +
                                          ((((t >> 1) * 4 + quad) ^ (row16 & 7)) * 8)];
        __builtin_amdgcn_s_setprio(1);
#pragma unroll
        for (int rg = 0; rg < 2; ++rg) {
            lacc[rg] = __builtin_amdgcn_mfma_f32_16x16x32_bf16(
                ap[rg], vone, lacc[rg], 0, 0, 0);
#pragma unroll
            for (int t = 0; t < 4; ++t)
                oacc[rg][t] = __builtin_amdgcn_mfma_f32_16x16x32_bf16(
                    ap[rg], bv[t], oacc[rg][t], 0, 0, 0);
        }
        __builtin_amdgcn_s_setprio(0);
    };

    // ---- one 64-key iteration; kb/vb current bufs, kn/vn stage targets ----
    auto iter = [&](const ushort* kb, const ushort* vb,
                    ushort* kn, ushort* vn, bool st) {
        unsigned m0lo = mptr[0],    m0hi = mptr[16];
        unsigned m1lo = mptr[2048], m1hi = mptr[2048 + 16];
        mptr += 4096;
        __builtin_amdgcn_sched_barrier(0);         // masks issue BEFORE stages
        if (st) {                                  // stage tile kt+2
            if (isK) {
                GLD_LDS16(kstage,        kn + (wk * 8) * 64);
                GLD_LDS16(kstage + 2048, kn + (32 + wk * 8) * 64);
                kstage += 4096;
            } else {
                GLD_LDS16(vstage,      vn + (wk * 8) * 64);
                GLD_LDS16(vstage + 32, vn + (32 + wk * 8) * 64);
                vstage += 64;
            }
        }
        f32x4 s0[2][2];
        qk(kb, 0, s0);
        sm_pv(s0, m0lo, m0hi, vb, 0);              // mask-wait retires stage(kt+1)
        f32x4 s1[2][2];
        qk(kb, 1, s1);
        sm_pv(s1, m1lo, m1hi, vb, 1);
        asm volatile("s_waitcnt vmcnt(2)" ::: "memory");  // stage(kt+2) stays in flight
        __builtin_amdgcn_s_barrier();
        __builtin_amdgcn_sched_barrier(0);         // no ds_read hoist above barrier
    };

    // prologue barrier: tile-0 loads done (vmcnt(2): tile-1's 2 may fly)
    asm volatile("s_waitcnt vmcnt(2)" ::: "memory");
    __builtin_amdgcn_s_barrier();
    __builtin_amdgcn_sched_barrier(0);

    // 32 iterations, buffers cycle mod 3: kt=3g..3g+2 for g=0..9, then 30,31.
    for (int g = 0; g < 10; ++g) {
        iter(KV[0], KV[3], KV[2], KV[5], true);    // kt=3g:   read buf0, stage buf2
        iter(KV[1], KV[4], KV[0], KV[3], true);    // kt=3g+1: read buf1, stage buf0
        iter(KV[2], KV[5], KV[1], KV[4], true);    // kt=3g+2: read buf2, stage buf1
    }
    iter(KV[0], KV[3], KV[2], KV[5], false);       // kt=30
    iter(KV[1], KV[4], KV[0], KV[3], false);       // kt=31

    // ---- epilogue: /l (0 if fully masked), write vals bf16 [T][E] ----
#pragma unroll
    for (int rg = 0; rg < 2; ++rg)
#pragma unroll
        for (int r = 0; r < 4; ++r) {
            float l = lacc[rg][r];
            float inv = (l > 0.f) ? 1.0f / l : 0.f;
            int qrow = q0 + wv * 32 + rg * 16 + quad * 4 + r;
            size_t base = ((size_t)b * L_ + qrow) * E_ + h * 64;
#pragma unroll
            for (int t = 0; t < 4; ++t)
                vals[base + t * 16 + row16] = f2b(oacc[rg][t][r] * inv);
        }
}

// ---------------------------------------------------------------------------
// Launch
// ---------------------------------------------------------------------------
extern "C" void kernel_launch(void* const* d_in, const int* in_sizes, int n_in,
                              void* d_out, int out_size, void* d_ws, size_t ws_size,
                              hipStream_t stream) {
    const float* emb  = (const float*)d_in[0];
    const void*  mask = d_in[1];
    const float* wqkv = (const float*)d_in[2];
    const float* wout = (const float*)d_in[3];
    float* out = (float*)d_out;

    char* ws = (char*)d_ws;
    const size_t NEED = 4096ull + 2097152ull + 2ull * 46137344ull;
    if (ws_size < NEED) return;

    int* flag = (int*)ws;
    unsigned* tbits = (unsigned*)(ws + 4096);          // 2 MB, [b][w32][q]
    ushort* embb  = (ushort*)(ws + 4096 + 2097152);
    ushort* Wqkvt = embb  + 8388608;   // [3072][1024]
    ushort* Wott  = Wqkvt + 3145728;   // [1024][1024]
    ushort* Qb    = Wott  + 1048576;   // [B*H][L][A]  (pre-scaled by CSC_)
    ushort* Kb    = Qb    + 8388608;   // [B*H][L][A]
    ushort* Vt    = Kb    + 8388608;   // [B*H][A][L]  (key-permuted in 32-groups)
    ushort* vals  = Vt    + 8388608;   // [T][E] bf16

    detect_mask_layout<<<1, 256, 0, stream>>>((const unsigned char*)mask, flag);
    pack_mask<<<T_, 256, 0, stream>>>(mask, flag, tbits);
    conv_bf16<<<8192, 256, 0, stream>>>(emb, embb);
    transpose_conv<<<dim3(96, 32), 256, 0, stream>>>(wqkv, Wqkvt, 1024, 3072);
    transpose_conv<<<dim3(32, 32), 256, 0, stream>>>(wout, Wott, 1024, 1024);
    gemm_bf16<3072, 1><<<dim3(24, 64), 256, 0, stream>>>(
        embb, Wqkvt, nullptr, Qb, Kb, Vt);
    attn_mfma<<<dim3(64, 8), 512, 0, stream>>>(Qb, Kb, Vt, tbits, vals);
    gemm_bf16<1024, 0><<<dim3(8, 64), 256, 0, stream>>>(
        vals, Wott, out, nullptr, nullptr, nullptr);
}